// Round 11
// baseline (217.880 us; speedup 1.0000x reference)
//
#include <hip/hip_runtime.h>
#include <math.h>

// DP-GCN constants (EPS=1, ALPHA=0.5, DELTA=1):
//   transformed = ((e+1)*x - 1) * (1/(e-1)) + 0.5 = C1*x + C0
#define C1 2.163953413738653f
#define C0 -0.081976706869326f

// NOTE: assumes N <= 65536 so node ids fit u16 (N=50000 here).

typedef __attribute__((ext_vector_type(8))) short bf16x8;
typedef __attribute__((ext_vector_type(4))) float f32x4;

static __device__ __forceinline__ unsigned short f2bf(float f) {   // RTN-even
    unsigned b = __float_as_uint(f);
    return (unsigned short)((b + 0x7FFFu + ((b >> 16) & 1u)) >> 16);
}
static __device__ __forceinline__ float bf2f(unsigned short u) {
    return __uint_as_float((unsigned)u << 16);
}

// ---- dual per-block histogram of col>>8 / row>>8; blocks 0/1 also convert W1/W2
// to bf16 swizzled into MFMA B-fragment order. hist[d*256+b] cols, [65536+d*256+b] rows.
__global__ __launch_bounds__(1024) void k_hist2(const int* __restrict__ row,
                                                const int* __restrict__ col, int E, int chunk,
                                                int* __restrict__ hist,
                                                const float* __restrict__ W1,
                                                const float* __restrict__ W2,
                                                unsigned short* __restrict__ W1b,
                                                unsigned short* __restrict__ W2b) {
    __shared__ int hc[256], hr[256];
    int t = threadIdx.x, b = blockIdx.x;
    if (t < 256) { hc[t] = 0; hr[t] = 0; }
    __syncthreads();
    int lo = b * chunk, hi = min(E, lo + chunk);
    for (int i = lo + t; i < hi; i += 1024) {
        atomicAdd(&hc[col[i] >> 8], 1);
        atomicAdd(&hr[row[i] >> 8], 1);
    }
    __syncthreads();
    if (t < 256) {
        hist[t * 256 + b] = hc[t];
        hist[65536 + t * 256 + b] = hr[t];
    }
    // B-fragment swizzle: frag element j of lane l for (ntile, ktile) holds
    // B[k = kt*32 + (l>>4)*8 + j][n = nt*16 + (l&15)], stored contiguously.
    if (b == 0) {
        for (int i = t; i < 8192; i += 1024) {           // W1: 8 nt x 2 kt
            int j = i & 7, l2 = (i >> 3) & 63, kt = (i >> 9) & 1, nt = i >> 10;
            int k = kt * 32 + (l2 >> 4) * 8 + j, n = nt * 16 + (l2 & 15);
            W1b[i] = f2bf(W1[k * 128 + n]);
        }
    } else if (b == 1) {
        for (int i = t; i < 4096; i += 1024) {           // W2: 2 nt x 4 kt
            int j = i & 7, l2 = (i >> 3) & 63, kt = (i >> 9) & 3, nt = i >> 11;
            int k = kt * 32 + (l2 >> 4) * 8 + j, n = nt * 16 + (l2 & 15);
            W2b[i] = f2bf(W2[k * 32 + n]);
        }
    }
}

// ---- partition, self-contained: each block derives its own scatter offsets
// from the raw hist (column prefix + digit-level scan); block 0 exports digit
// totals to dtot[512] for k_build. Then scatters edges/rows by top-8 digit.
__global__ __launch_bounds__(1024) void k_part(const int* __restrict__ row,
                                               const int* __restrict__ col, int E, int chunk,
                                               const int* __restrict__ hist,
                                               int* __restrict__ dtot,
                                               unsigned* __restrict__ cbuf,
                                               int* __restrict__ rbuf) {
    __shared__ int Tc[256], Pc[256], Tr[256], Pr[256], sc[256];
    __shared__ int offc[256], offr[256];
    int t = threadIdx.x, b = blockIdx.x;
    if (t < 256) { Tc[t] = 0; Pc[t] = 0; Tr[t] = 0; Pr[t] = 0; }
    __syncthreads();
    {
        int d = t & 255, g = t >> 8;         // 4 threads per digit
        int sT = 0, sP = 0, sTr = 0, sPr = 0;
        for (int b2 = g * 64; b2 < g * 64 + 64; ++b2) {
            int v = hist[d * 256 + b2];
            int w = hist[65536 + d * 256 + b2];
            sT += v; sTr += w;
            if (b2 < b) { sP += v; sPr += w; }
        }
        atomicAdd(&Tc[d], sT); atomicAdd(&Pc[d], sP);
        atomicAdd(&Tr[d], sTr); atomicAdd(&Pr[d], sPr);
    }
    __syncthreads();
    if (b == 0 && t < 256) { dtot[t] = Tc[t]; dtot[256 + t] = Tr[t]; }
    // exclusive scan of Tc -> offc base
    if (t < 256) sc[t] = Tc[t];
    __syncthreads();
    for (int off = 1; off < 256; off <<= 1) {
        int u = (t < 256 && t >= off) ? sc[t - off] : 0;
        __syncthreads();
        if (t < 256) sc[t] += u;
        __syncthreads();
    }
    if (t < 256) offc[t] = sc[t] - Tc[t] + Pc[t];
    __syncthreads();
    if (t < 256) sc[t] = Tr[t];
    __syncthreads();
    for (int off = 1; off < 256; off <<= 1) {
        int u = (t < 256 && t >= off) ? sc[t - off] : 0;
        __syncthreads();
        if (t < 256) sc[t] += u;
        __syncthreads();
    }
    if (t < 256) offr[t] = sc[t] - Tr[t] + Pr[t];
    __syncthreads();
    int lo = b * chunk, hi = min(E, lo + chunk);
    for (int i = lo + t; i < hi; i += 1024) {
        int r = row[i], c = col[i];
        int pc = atomicAdd(&offc[c >> 8], 1);
        cbuf[pc] = ((unsigned)c << 16) | (unsigned)r;
        int pr = atomicAdd(&offr[r >> 8], 1);
        rbuf[pr] = r;
    }
}

// ---- merged per-bucket build: blocks [0,nbk) deg->dis->xt; [nbk,2nbk) CSR ----
__global__ __launch_bounds__(256) void k_build(const int* __restrict__ rbuf,
                                               const unsigned* __restrict__ cbuf,
                                               const int* __restrict__ dtot,
                                               const int* __restrict__ priv,
                                               const float* __restrict__ x, int N, int E, int nbk,
                                               float* __restrict__ dis,
                                               unsigned short* __restrict__ xt,
                                               int* __restrict__ cntC, int* __restrict__ colStart,
                                               int* __restrict__ eSrc) {
    __shared__ int s1[256], s2[256], s3[256];
    int t = threadIdx.x;
    if ((int)blockIdx.x < nbk) {
        // ---- deg -> dis -> bf16 xt ----
        int b = blockIdx.x;
        s1[t] = (t < b) ? dtot[256 + t] : 0;   // prefix of row-digit totals
        __syncthreads();
        for (int off = 128; off > 0; off >>= 1) {
            if (t < off) s1[t] += s1[t + off];
            __syncthreads();
        }
        int rs = s1[0];
        int re = rs + dtot[256 + b];
        __syncthreads();
        s1[t] = 0;
        __syncthreads();
        for (int i = rs + t; i < re; i += 256) atomicAdd(&s1[rbuf[i] & 255], 1);
        __syncthreads();
        int node = b * 256 + t;
        float dv = rsqrtf((float)(s1[t] + 1));       // +1 self loop
        if (node < N) {
            dis[node] = dv;
            s2[t] = __float_as_int(dv);
            s3[t] = priv[node];
        } else { s2[t] = 0; s3[t] = 0; }
        __syncthreads();
        int base = b * 256;
        for (int i = t; i < 256 * 16; i += 256) {     // 16 float4 per node
            int ln = i >> 4;
            int n2 = base + ln;
            if (n2 >= N) continue;
            float d2 = __int_as_float(s2[ln]);
            int p = s3[ln];
            float4 v = ((const float4*)x)[(size_t)n2 * 16 + (i & 15)];
            float4 tr;
            tr.x = p ? fmaf(C1, v.x, C0) : v.x;
            tr.y = p ? fmaf(C1, v.y, C0) : v.y;
            tr.z = p ? fmaf(C1, v.z, C0) : v.z;
            tr.w = p ? fmaf(C1, v.w, C0) : v.w;
            ushort4 o;
            o.x = f2bf(d2 * tr.x); o.y = f2bf(d2 * tr.y);
            o.z = f2bf(d2 * tr.z); o.w = f2bf(d2 * tr.w);
            ((ushort4*)xt)[(size_t)n2 * 16 + (i & 15)] = o;
        }
    } else {
        // ---- CSR: cntC/colStart + eSrc[pos] = row (int) ----
        int b = blockIdx.x - nbk;
        s1[t] = (t < b) ? dtot[t] : 0;          // prefix of col-digit totals
        __syncthreads();
        for (int off = 128; off > 0; off >>= 1) {
            if (t < off) s1[t] += s1[t + off];
            __syncthreads();
        }
        int cs = s1[0];
        int ce = cs + dtot[b];
        __syncthreads();
        s1[t] = 0; s3[t] = 0;
        __syncthreads();
        for (int i = cs + t; i < ce; i += 256) atomicAdd(&s1[(cbuf[i] >> 16) & 255], 1);
        __syncthreads();
        int v = s1[t];
        s2[t] = v;
        __syncthreads();
        for (int off = 1; off < 256; off <<= 1) {
            int u = (t >= off) ? s2[t - off] : 0;
            __syncthreads();
            s2[t] += u;
            __syncthreads();
        }
        int excl = s2[t] - v;
        int c = b * 256 + t;
        if (c < N) { cntC[c] = v; colStart[c] = cs + excl; }
        __syncthreads();
        s2[t] = excl;
        __syncthreads();
        for (int i = cs + t; i < ce; i += 256) {
            unsigned e = cbuf[i];
            int d = (e >> 16) & 255;
            int pos = cs + s2[d] + atomicAdd(&s3[d], 1);
            eSrc[pos] = (int)(e & 0xFFFFu);
        }
    }
}

// conv1 by gather: agg1b[c] = bf16( dis_c * (xt_c + sum_r xt_r) ); wave per c.
// Edge ids read as wave-uniform scalar loads (no shfl), 8 xt loads in flight.
__global__ __launch_bounds__(256) void k_gather1(const unsigned short* __restrict__ xt,
                                                 const int* __restrict__ eSrcI,
                                                 const int* __restrict__ colStart,
                                                 const int* __restrict__ cntC,
                                                 const float* __restrict__ dis,
                                                 unsigned short* __restrict__ agg1b, int N) {
    int t = blockIdx.x * blockDim.x + threadIdx.x;
    int c = t >> 6, d = t & 63;
    if (c >= N) return;
    int start = __builtin_amdgcn_readfirstlane(colStart[c]);
    int cnt   = __builtin_amdgcn_readfirstlane(cntC[c]);
    float s = bf2f(xt[(size_t)c * 64 + d]);   // self loop term
    const int* ep = eSrcI + start;
    int k = 0;
    for (; k + 8 <= cnt; k += 8) {
        int r0 = ep[k],     r1 = ep[k + 1], r2 = ep[k + 2], r3 = ep[k + 3];
        int r4 = ep[k + 4], r5 = ep[k + 5], r6 = ep[k + 6], r7 = ep[k + 7];
        float x0 = bf2f(xt[(size_t)r0 * 64 + d]);
        float x1 = bf2f(xt[(size_t)r1 * 64 + d]);
        float x2 = bf2f(xt[(size_t)r2 * 64 + d]);
        float x3 = bf2f(xt[(size_t)r3 * 64 + d]);
        float x4 = bf2f(xt[(size_t)r4 * 64 + d]);
        float x5 = bf2f(xt[(size_t)r5 * 64 + d]);
        float x6 = bf2f(xt[(size_t)r6 * 64 + d]);
        float x7 = bf2f(xt[(size_t)r7 * 64 + d]);
        s += x0; s += x1; s += x2; s += x3;
        s += x4; s += x5; s += x6; s += x7;
    }
    for (; k < cnt; ++k) {
        int r = ep[k];
        s += bf2f(xt[(size_t)r * 64 + d]);
    }
    agg1b[(size_t)c * 64 + d] = f2bf(dis[c] * s);
}

// ---- MFMA MLP: hps = bf16(dis * (relu(A@W1+b1)@W2)); 64-node tile, 4 waves ----
__global__ __launch_bounds__(256) void k_mlp_mfma(const unsigned short* __restrict__ agg1b,
                                                  const unsigned short* __restrict__ W1b,
                                                  const float* __restrict__ b1,
                                                  const unsigned short* __restrict__ W2b,
                                                  const float* __restrict__ dis,
                                                  unsigned short* __restrict__ hps, int N) {
    __shared__ unsigned short hidA[4][16 * 136];   // per-wave 16 x 128 (+8 pad)
    const int t = threadIdx.x;
    const int w = t >> 6, l = t & 63;
    const int q = l >> 4, lm = l & 15;
    const int rowbase = blockIdx.x * 64 + w * 16;

    bf16x8 a0, a1;
    {
        int node = rowbase + lm;
        if (node >= N) node = N - 1;
        const bf16x8* pa = (const bf16x8*)(agg1b + (size_t)node * 64);
        a0 = pa[q];
        a1 = pa[4 + q];
    }
    float dvals[4];
    #pragma unroll
    for (int r = 0; r < 4; ++r) {
        int node = rowbase + q * 4 + r;
        dvals[r] = (node < N) ? dis[node] : 0.f;
    }

    const bf16x8* w1f = (const bf16x8*)W1b;
    #pragma unroll
    for (int nt = 0; nt < 8; ++nt) {
        float bv = b1[nt * 16 + lm];
        f32x4 acc = {bv, bv, bv, bv};
        acc = __builtin_amdgcn_mfma_f32_16x16x32_bf16(a0, w1f[(nt * 2 + 0) * 64 + l], acc, 0, 0, 0);
        acc = __builtin_amdgcn_mfma_f32_16x16x32_bf16(a1, w1f[(nt * 2 + 1) * 64 + l], acc, 0, 0, 0);
        #pragma unroll
        for (int r = 0; r < 4; ++r)
            hidA[w][(q * 4 + r) * 136 + nt * 16 + lm] = f2bf(fmaxf(acc[r], 0.f));
    }
    __syncthreads();

    bf16x8 ha[4];
    #pragma unroll
    for (int kt = 0; kt < 4; ++kt)
        ha[kt] = *(const bf16x8*)&hidA[w][lm * 136 + kt * 32 + q * 8];

    const bf16x8* w2f = (const bf16x8*)W2b;
    #pragma unroll
    for (int nt = 0; nt < 2; ++nt) {
        f32x4 acc = {0.f, 0.f, 0.f, 0.f};
        #pragma unroll
        for (int kt = 0; kt < 4; ++kt)
            acc = __builtin_amdgcn_mfma_f32_16x16x32_bf16(ha[kt], w2f[(nt * 4 + kt) * 64 + l], acc, 0, 0, 0);
        #pragma unroll
        for (int r = 0; r < 4; ++r) {
            int node = rowbase + q * 4 + r;
            if (node < N)
                hps[(size_t)node * 32 + nt * 16 + lm] = f2bf(acc[r] * dvals[r]);
        }
    }
}

// conv2 by gather: out[c] = b2 - dis_c * (hps_c + sum_r hps_r).
// 64 lanes per node: halves process alternating edges, butterfly-combine at end.
__global__ __launch_bounds__(256) void k_gather2(const unsigned short* __restrict__ hps,
                                                 const int* __restrict__ eSrcI,
                                                 const int* __restrict__ colStart,
                                                 const int* __restrict__ cntC,
                                                 const float* __restrict__ dis,
                                                 const float* __restrict__ b2,
                                                 float* __restrict__ out, int N) {
    int t = blockIdx.x * blockDim.x + threadIdx.x;
    int c = t >> 6, l = t & 63;
    int j = l & 31, half = l >> 5;
    if (c >= N) return;
    int start = __builtin_amdgcn_readfirstlane(colStart[c]);
    int cnt   = __builtin_amdgcn_readfirstlane(cntC[c]);
    float s = half ? 0.f : bf2f(hps[(size_t)c * 32 + j]);   // self loop counted once
    const int* ep = eSrcI + start;
    int k = 0;
    for (; k + 8 <= cnt; k += 8) {
        int a0 = ep[k],     e0 = ep[k + 1], a1 = ep[k + 2], e1 = ep[k + 3];
        int a2 = ep[k + 4], e2 = ep[k + 5], a3 = ep[k + 6], e3 = ep[k + 7];
        int r0 = half ? e0 : a0;
        int r1 = half ? e1 : a1;
        int r2 = half ? e2 : a2;
        int r3 = half ? e3 : a3;
        float h0 = bf2f(hps[(size_t)r0 * 32 + j]);
        float h1 = bf2f(hps[(size_t)r1 * 32 + j]);
        float h2 = bf2f(hps[(size_t)r2 * 32 + j]);
        float h3 = bf2f(hps[(size_t)r3 * 32 + j]);
        s += h0; s += h1; s += h2; s += h3;
    }
    for (; k + 2 <= cnt; k += 2) {
        int a = ep[k], e = ep[k + 1];
        int r = half ? e : a;
        s += bf2f(hps[(size_t)r * 32 + j]);
    }
    if (k < cnt && !half) {
        int r = ep[k];
        s += bf2f(hps[(size_t)r * 32 + j]);
    }
    float o = __shfl(s, l ^ 32);   // combine the two halves
    s += o;
    if (!half)
        out[(size_t)c * 32 + j] = b2[j] - dis[c] * s;
}

extern "C" void kernel_launch(void* const* d_in, const int* in_sizes, int n_in,
                              void* d_out, int out_size, void* d_ws, size_t ws_size,
                              hipStream_t stream) {
    const float* x    = (const float*)d_in[0];
    const int*   ei   = (const int*)d_in[1];
    const int*   priv = (const int*)d_in[2];
    const float* W1   = (const float*)d_in[3];
    const float* b1   = (const float*)d_in[4];
    const float* W2   = (const float*)d_in[5];
    const float* b2   = (const float*)d_in[6];
    float* out = (float*)d_out;

    const int N = in_sizes[2];
    const int E = in_sizes[1] / 2;
    const int* row = ei;
    const int* col = ei + E;

    char* ws = (char*)d_ws;
    size_t off = 0;
    auto take = [&](size_t bytes) { char* p = ws + off; off = (off + bytes + 255) & ~(size_t)255; return p; };
    int*            hist     = (int*)           take((size_t)131072 * 4);
    int*            dtot     = (int*)           take(512 * 4);
    unsigned short* W1b      = (unsigned short*)take((size_t)8192 * 2);
    unsigned short* W2b      = (unsigned short*)take((size_t)4096 * 2);
    unsigned*       cbuf     = (unsigned*)      take((size_t)E * 4);
    int*            rbuf     = (int*)           take((size_t)E * 4);
    float*          dis      = (float*)         take((size_t)N * 4);
    int*            cntC     = (int*)           take((size_t)N * 4);
    int*            colStart = (int*)           take((size_t)N * 4);
    int*            eSrcI    = (int*)           take((size_t)E * 4);
    unsigned short* xt       = (unsigned short*)take((size_t)N * 64 * 2);
    unsigned short* agg1b    = (unsigned short*)take((size_t)N * 64 * 2);
    unsigned short* hps      = (unsigned short*)take((size_t)N * 32 * 2);
    (void)ws_size;

    const int chunk = (E + 255) / 256;
    const int nbk = (N + 255) / 256;     // node buckets (196 < 255)

    k_hist2   <<<256, 1024, 0, stream>>>(row, col, E, chunk, hist, W1, W2, W1b, W2b);
    k_part    <<<256, 1024, 0, stream>>>(row, col, E, chunk, hist, dtot, cbuf, rbuf);
    k_build   <<<2 * nbk, 256, 0, stream>>>(rbuf, cbuf, dtot, priv, x, N, E, nbk,
                                            dis, xt, cntC, colStart, eSrcI);
    k_gather1 <<<((size_t)N * 64 + 255) / 256, 256, 0, stream>>>(xt, eSrcI, colStart, cntC, dis, agg1b, N);
    k_mlp_mfma<<<(N + 63) / 64, 256, 0, stream>>>(agg1b, W1b, b1, W2b, dis, hps, N);
    k_gather2 <<<((size_t)N * 64 + 255) / 256, 256, 0, stream>>>(hps, eSrcI, colStart, cntC, dis, b2, out, N);
}

// Round 12
// 155.926 us; speedup vs baseline: 1.3973x; 1.3973x over previous
//
#include <hip/hip_runtime.h>
#include <math.h>

// DP-GCN constants (EPS=1, ALPHA=0.5, DELTA=1):
//   transformed = ((e+1)*x - 1) * (1/(e-1)) + 0.5 = C1*x + C0
#define C1 2.163953413738653f
#define C0 -0.081976706869326f

// NOTE: assumes N <= 65536 so node ids fit u16 (N=50000 here).

typedef __attribute__((ext_vector_type(8))) short bf16x8;
typedef __attribute__((ext_vector_type(4))) float f32x4;

static __device__ __forceinline__ unsigned short f2bf(float f) {   // RTN-even
    unsigned b = __float_as_uint(f);
    return (unsigned short)((b + 0x7FFFu + ((b >> 16) & 1u)) >> 16);
}
static __device__ __forceinline__ float bf2f(unsigned short u) {
    return __uint_as_float((unsigned)u << 16);
}

// ---- dual per-block histogram of col>>8 / row>>8; blocks 0/1 also convert W1/W2
// to bf16 swizzled into MFMA B-fragment order. hist[d*256+b] cols, [65536+d*256+b] rows.
// chunk is a multiple of 4 so &row[lo] is 16B-aligned for int4 loads.
__global__ __launch_bounds__(1024) void k_hist2(const int* __restrict__ row,
                                                const int* __restrict__ col, int E, int chunk,
                                                int* __restrict__ hist,
                                                const float* __restrict__ W1,
                                                const float* __restrict__ W2,
                                                unsigned short* __restrict__ W1b,
                                                unsigned short* __restrict__ W2b) {
    __shared__ int hc[256], hr[256];
    int t = threadIdx.x, b = blockIdx.x;
    if (t < 256) { hc[t] = 0; hr[t] = 0; }
    __syncthreads();
    int lo = b * chunk, hi = min(E, lo + chunk);
    int base = lo + t * 4;
    for (; base + 3 < hi; base += 4096) {
        int4 r4 = *(const int4*)&row[base];
        int4 c4 = *(const int4*)&col[base];
        atomicAdd(&hc[c4.x >> 8], 1); atomicAdd(&hc[c4.y >> 8], 1);
        atomicAdd(&hc[c4.z >> 8], 1); atomicAdd(&hc[c4.w >> 8], 1);
        atomicAdd(&hr[r4.x >> 8], 1); atomicAdd(&hr[r4.y >> 8], 1);
        atomicAdd(&hr[r4.z >> 8], 1); atomicAdd(&hr[r4.w >> 8], 1);
    }
    for (; base < hi; ++base) {
        atomicAdd(&hc[col[base] >> 8], 1);
        atomicAdd(&hr[row[base] >> 8], 1);
    }
    __syncthreads();
    if (t < 256) {
        hist[t * 256 + b] = hc[t];
        hist[65536 + t * 256 + b] = hr[t];
    }
    // B-fragment swizzle: frag element j of lane l for (ntile, ktile) holds
    // B[k = kt*32 + (l>>4)*8 + j][n = nt*16 + (l&15)], stored contiguously.
    if (b == 0) {
        for (int i = t; i < 8192; i += 1024) {           // W1: 8 nt x 2 kt
            int j = i & 7, l2 = (i >> 3) & 63, kt = (i >> 9) & 1, nt = i >> 10;
            int k = kt * 32 + (l2 >> 4) * 8 + j, n = nt * 16 + (l2 & 15);
            W1b[i] = f2bf(W1[k * 128 + n]);
        }
    } else if (b == 1) {
        for (int i = t; i < 4096; i += 1024) {           // W2: 2 nt x 4 kt
            int j = i & 7, l2 = (i >> 3) & 63, kt = (i >> 9) & 3, nt = i >> 11;
            int k = kt * 32 + (l2 >> 4) * 8 + j, n = nt * 16 + (l2 & 15);
            W2b[i] = f2bf(W2[k * 32 + n]);
        }
    }
}

// ---- level-1 exclusive scan: scan-block d = digit d's 256 per-block counts.
// excl[d*256+b] = within-digit prefix over blocks<b; bsum[d] = digit total.
__global__ void k_scan_a(const int* __restrict__ cnt, int* __restrict__ excl,
                         int* __restrict__ bsum, int n) {
    __shared__ int s[256];
    int idx = blockIdx.x * 256 + threadIdx.x;
    int v = (idx < n) ? cnt[idx] : 0;
    s[threadIdx.x] = v;
    __syncthreads();
    for (int off = 1; off < 256; off <<= 1) {
        int t = (threadIdx.x >= off) ? s[threadIdx.x - off] : 0;
        __syncthreads();
        s[threadIdx.x] += t;
        __syncthreads();
    }
    if (idx < n) excl[idx] = s[threadIdx.x] - v;
    if (threadIdx.x == 255) bsum[blockIdx.x] = s[255];
}

// ---- partition: digit bases from bsum (two concurrent 256-scans), then scatter.
__global__ __launch_bounds__(1024) void k_part(const int* __restrict__ row,
                                               const int* __restrict__ col, int E, int chunk,
                                               const int* __restrict__ excl,
                                               const int* __restrict__ bsum,
                                               unsigned* __restrict__ cbuf,
                                               unsigned short* __restrict__ rbuf) {
    __shared__ int sc[512];
    __shared__ int offc[256], offr[256];
    int t = threadIdx.x, b = blockIdx.x;
    // concurrent exclusive scans: lanes 0-255 col digits, 256-511 row digits
    if (t < 512) sc[t] = bsum[t];
    __syncthreads();
    int half = t >> 8, d = t & 255;
    for (int off = 1; off < 256; off <<= 1) {
        int u = (t < 512 && d >= off) ? sc[half * 256 + d - off] : 0;
        __syncthreads();
        if (t < 512) sc[t] += u;
        __syncthreads();
    }
    if (t < 256) offc[t] = sc[t] - bsum[t] + excl[t * 256 + b];
    else if (t < 512) offr[d] = sc[t] - bsum[t] + excl[65536 + d * 256 + b];
    __syncthreads();
    int lo = b * chunk, hi = min(E, lo + chunk);
    int base = lo + t * 4;
    for (; base + 3 < hi; base += 4096) {
        int4 r4 = *(const int4*)&row[base];
        int4 c4 = *(const int4*)&col[base];
        int p0 = atomicAdd(&offc[c4.x >> 8], 1);
        cbuf[p0] = ((unsigned)c4.x << 16) | (unsigned)r4.x;
        int p1 = atomicAdd(&offc[c4.y >> 8], 1);
        cbuf[p1] = ((unsigned)c4.y << 16) | (unsigned)r4.y;
        int p2 = atomicAdd(&offc[c4.z >> 8], 1);
        cbuf[p2] = ((unsigned)c4.z << 16) | (unsigned)r4.z;
        int p3 = atomicAdd(&offc[c4.w >> 8], 1);
        cbuf[p3] = ((unsigned)c4.w << 16) | (unsigned)r4.w;
        int q0 = atomicAdd(&offr[r4.x >> 8], 1); rbuf[q0] = (unsigned short)r4.x;
        int q1 = atomicAdd(&offr[r4.y >> 8], 1); rbuf[q1] = (unsigned short)r4.y;
        int q2 = atomicAdd(&offr[r4.z >> 8], 1); rbuf[q2] = (unsigned short)r4.z;
        int q3 = atomicAdd(&offr[r4.w >> 8], 1); rbuf[q3] = (unsigned short)r4.w;
    }
    for (; base < hi; ++base) {
        int r = row[base], c = col[base];
        int pc = atomicAdd(&offc[c >> 8], 1);
        cbuf[pc] = ((unsigned)c << 16) | (unsigned)r;
        int pr = atomicAdd(&offr[r >> 8], 1);
        rbuf[pr] = (unsigned short)r;
    }
}

// ---- merged per-bucket build: blocks [0,nbk) deg->dis->xt; [nbk,2nbk) CSR ----
__global__ __launch_bounds__(256) void k_build(const unsigned short* __restrict__ rbuf,
                                               const unsigned* __restrict__ cbuf,
                                               const int* __restrict__ bsum,
                                               const int* __restrict__ priv,
                                               const float* __restrict__ x, int N, int E, int nbk,
                                               float* __restrict__ dis,
                                               unsigned short* __restrict__ xt,
                                               int* __restrict__ cntC, int* __restrict__ colStart,
                                               unsigned short* __restrict__ eSrc) {
    __shared__ int s1[256], s2[256], s3[256];
    int t = threadIdx.x;
    if ((int)blockIdx.x < nbk) {
        // ---- deg -> dis -> bf16 xt ----
        int b = blockIdx.x;
        s1[t] = (t < b) ? bsum[256 + t] : 0;   // prefix of row-digit totals
        __syncthreads();
        for (int off = 128; off > 0; off >>= 1) {
            if (t < off) s1[t] += s1[t + off];
            __syncthreads();
        }
        int rs = s1[0];
        int re = rs + bsum[256 + b];
        __syncthreads();
        s1[t] = 0;
        __syncthreads();
        for (int i = rs + t; i < re; i += 256) atomicAdd(&s1[rbuf[i] & 255], 1);
        __syncthreads();
        int node = b * 256 + t;
        float dv = rsqrtf((float)(s1[t] + 1));       // +1 self loop
        if (node < N) {
            dis[node] = dv;
            s2[t] = __float_as_int(dv);
            s3[t] = priv[node];
        } else { s2[t] = 0; s3[t] = 0; }
        __syncthreads();
        int base = b * 256;
        for (int i = t; i < 256 * 16; i += 256) {     // 16 float4 per node
            int ln = i >> 4;
            int n2 = base + ln;
            if (n2 >= N) continue;
            float d2 = __int_as_float(s2[ln]);
            int p = s3[ln];
            float4 v = ((const float4*)x)[(size_t)n2 * 16 + (i & 15)];
            float4 tr;
            tr.x = p ? fmaf(C1, v.x, C0) : v.x;
            tr.y = p ? fmaf(C1, v.y, C0) : v.y;
            tr.z = p ? fmaf(C1, v.z, C0) : v.z;
            tr.w = p ? fmaf(C1, v.w, C0) : v.w;
            ushort4 o;
            o.x = f2bf(d2 * tr.x); o.y = f2bf(d2 * tr.y);
            o.z = f2bf(d2 * tr.z); o.w = f2bf(d2 * tr.w);
            ((ushort4*)xt)[(size_t)n2 * 16 + (i & 15)] = o;
        }
    } else {
        // ---- CSR: cntC/colStart + eSrc[pos] = row (u16) ----
        int b = blockIdx.x - nbk;
        s1[t] = (t < b) ? bsum[t] : 0;          // prefix of col-digit totals
        __syncthreads();
        for (int off = 128; off > 0; off >>= 1) {
            if (t < off) s1[t] += s1[t + off];
            __syncthreads();
        }
        int cs = s1[0];
        int ce = cs + bsum[b];
        __syncthreads();
        s1[t] = 0; s3[t] = 0;
        __syncthreads();
        for (int i = cs + t; i < ce; i += 256) atomicAdd(&s1[(cbuf[i] >> 16) & 255], 1);
        __syncthreads();
        int v = s1[t];
        s2[t] = v;
        __syncthreads();
        for (int off = 1; off < 256; off <<= 1) {
            int u = (t >= off) ? s2[t - off] : 0;
            __syncthreads();
            s2[t] += u;
            __syncthreads();
        }
        int excl = s2[t] - v;
        int c = b * 256 + t;
        if (c < N) { cntC[c] = v; colStart[c] = cs + excl; }
        __syncthreads();
        s2[t] = excl;
        __syncthreads();
        for (int i = cs + t; i < ce; i += 256) {
            unsigned e = cbuf[i];
            int d = (e >> 16) & 255;
            int pos = cs + s2[d] + atomicAdd(&s3[d], 1);
            eSrc[pos] = (unsigned short)(e & 0xFFFFu);
        }
    }
}

// conv1 by gather: agg1b[c] = bf16( dis_c * (xt_c + sum_r xt_r) ); wave per c, 8x unroll
__global__ __launch_bounds__(256) void k_gather1(const unsigned short* __restrict__ xt,
                                                 const unsigned short* __restrict__ eSrc,
                                                 const int* __restrict__ colStart,
                                                 const int* __restrict__ cntC,
                                                 const float* __restrict__ dis,
                                                 unsigned short* __restrict__ agg1b, int N) {
    int t = blockIdx.x * blockDim.x + threadIdx.x;
    int c = t >> 6, d = t & 63;
    if (c >= N) return;
    float s = bf2f(xt[(size_t)c * 64 + d]);   // self loop term
    int start = colStart[c], cnt = cntC[c];
    for (int base = 0; base < cnt; base += 64) {
        int m = min(cnt - base, 64);
        int ids = (d < m) ? (int)eSrc[start + base + d] : 0;
        int k = 0;
        for (; k + 8 <= m; k += 8) {
            int r0 = __shfl(ids, k),     r1 = __shfl(ids, k + 1);
            int r2 = __shfl(ids, k + 2), r3 = __shfl(ids, k + 3);
            int r4 = __shfl(ids, k + 4), r5 = __shfl(ids, k + 5);
            int r6 = __shfl(ids, k + 6), r7 = __shfl(ids, k + 7);
            float x0 = bf2f(xt[(size_t)r0 * 64 + d]);
            float x1 = bf2f(xt[(size_t)r1 * 64 + d]);
            float x2 = bf2f(xt[(size_t)r2 * 64 + d]);
            float x3 = bf2f(xt[(size_t)r3 * 64 + d]);
            float x4 = bf2f(xt[(size_t)r4 * 64 + d]);
            float x5 = bf2f(xt[(size_t)r5 * 64 + d]);
            float x6 = bf2f(xt[(size_t)r6 * 64 + d]);
            float x7 = bf2f(xt[(size_t)r7 * 64 + d]);
            s += x0; s += x1; s += x2; s += x3;
            s += x4; s += x5; s += x6; s += x7;
        }
        for (; k + 4 <= m; k += 4) {
            int r0 = __shfl(ids, k),     r1 = __shfl(ids, k + 1);
            int r2 = __shfl(ids, k + 2), r3 = __shfl(ids, k + 3);
            float x0 = bf2f(xt[(size_t)r0 * 64 + d]);
            float x1 = bf2f(xt[(size_t)r1 * 64 + d]);
            float x2 = bf2f(xt[(size_t)r2 * 64 + d]);
            float x3 = bf2f(xt[(size_t)r3 * 64 + d]);
            s += x0; s += x1; s += x2; s += x3;
        }
        for (; k < m; ++k) {
            int r = __shfl(ids, k);
            s += bf2f(xt[(size_t)r * 64 + d]);
        }
    }
    agg1b[(size_t)c * 64 + d] = f2bf(dis[c] * s);
}

// ---- MFMA MLP: hps = bf16(dis * (relu(A@W1+b1)@W2)); 64-node tile, 4 waves ----
__global__ __launch_bounds__(256) void k_mlp_mfma(const unsigned short* __restrict__ agg1b,
                                                  const unsigned short* __restrict__ W1b,
                                                  const float* __restrict__ b1,
                                                  const unsigned short* __restrict__ W2b,
                                                  const float* __restrict__ dis,
                                                  unsigned short* __restrict__ hps, int N) {
    __shared__ unsigned short hidA[4][16 * 136];   // per-wave 16 x 128 (+8 pad)
    const int t = threadIdx.x;
    const int w = t >> 6, l = t & 63;
    const int q = l >> 4, lm = l & 15;
    const int rowbase = blockIdx.x * 64 + w * 16;

    bf16x8 a0, a1;
    {
        int node = rowbase + lm;
        if (node >= N) node = N - 1;
        const bf16x8* pa = (const bf16x8*)(agg1b + (size_t)node * 64);
        a0 = pa[q];
        a1 = pa[4 + q];
    }
    float dvals[4];
    #pragma unroll
    for (int r = 0; r < 4; ++r) {
        int node = rowbase + q * 4 + r;
        dvals[r] = (node < N) ? dis[node] : 0.f;
    }

    const bf16x8* w1f = (const bf16x8*)W1b;
    #pragma unroll
    for (int nt = 0; nt < 8; ++nt) {
        float bv = b1[nt * 16 + lm];
        f32x4 acc = {bv, bv, bv, bv};
        acc = __builtin_amdgcn_mfma_f32_16x16x32_bf16(a0, w1f[(nt * 2 + 0) * 64 + l], acc, 0, 0, 0);
        acc = __builtin_amdgcn_mfma_f32_16x16x32_bf16(a1, w1f[(nt * 2 + 1) * 64 + l], acc, 0, 0, 0);
        #pragma unroll
        for (int r = 0; r < 4; ++r)
            hidA[w][(q * 4 + r) * 136 + nt * 16 + lm] = f2bf(fmaxf(acc[r], 0.f));
    }
    __syncthreads();

    bf16x8 ha[4];
    #pragma unroll
    for (int kt = 0; kt < 4; ++kt)
        ha[kt] = *(const bf16x8*)&hidA[w][lm * 136 + kt * 32 + q * 8];

    const bf16x8* w2f = (const bf16x8*)W2b;
    #pragma unroll
    for (int nt = 0; nt < 2; ++nt) {
        f32x4 acc = {0.f, 0.f, 0.f, 0.f};
        #pragma unroll
        for (int kt = 0; kt < 4; ++kt)
            acc = __builtin_amdgcn_mfma_f32_16x16x32_bf16(ha[kt], w2f[(nt * 4 + kt) * 64 + l], acc, 0, 0, 0);
        #pragma unroll
        for (int r = 0; r < 4; ++r) {
            int node = rowbase + q * 4 + r;
            if (node < N)
                hps[(size_t)node * 32 + nt * 16 + lm] = f2bf(acc[r] * dvals[r]);
        }
    }
}

// conv2 by gather: out[c] = b2 - dis_c * (hps_c + sum_r hps_r); 32 lanes per c, 8x unroll
__global__ __launch_bounds__(256) void k_gather2(const unsigned short* __restrict__ hps,
                                                 const unsigned short* __restrict__ eSrc,
                                                 const int* __restrict__ colStart,
                                                 const int* __restrict__ cntC,
                                                 const float* __restrict__ dis,
                                                 const float* __restrict__ b2,
                                                 float* __restrict__ out, int N) {
    int t = blockIdx.x * blockDim.x + threadIdx.x;
    int c = t >> 5, j = t & 31;
    if (c >= N) return;
    float s = bf2f(hps[(size_t)c * 32 + j]);   // self loop
    int start = colStart[c], cnt = cntC[c];
    for (int base = 0; base < cnt; base += 32) {
        int m = min(cnt - base, 32);
        int ids = (j < m) ? (int)eSrc[start + base + j] : 0;
        int k = 0;
        for (; k + 8 <= m; k += 8) {
            int r0 = __shfl(ids, k, 32),     r1 = __shfl(ids, k + 1, 32);
            int r2 = __shfl(ids, k + 2, 32), r3 = __shfl(ids, k + 3, 32);
            int r4 = __shfl(ids, k + 4, 32), r5 = __shfl(ids, k + 5, 32);
            int r6 = __shfl(ids, k + 6, 32), r7 = __shfl(ids, k + 7, 32);
            float h0 = bf2f(hps[(size_t)r0 * 32 + j]);
            float h1 = bf2f(hps[(size_t)r1 * 32 + j]);
            float h2 = bf2f(hps[(size_t)r2 * 32 + j]);
            float h3 = bf2f(hps[(size_t)r3 * 32 + j]);
            float h4 = bf2f(hps[(size_t)r4 * 32 + j]);
            float h5 = bf2f(hps[(size_t)r5 * 32 + j]);
            float h6 = bf2f(hps[(size_t)r6 * 32 + j]);
            float h7 = bf2f(hps[(size_t)r7 * 32 + j]);
            s += h0; s += h1; s += h2; s += h3;
            s += h4; s += h5; s += h6; s += h7;
        }
        for (; k + 4 <= m; k += 4) {
            int r0 = __shfl(ids, k, 32),     r1 = __shfl(ids, k + 1, 32);
            int r2 = __shfl(ids, k + 2, 32), r3 = __shfl(ids, k + 3, 32);
            float h0 = bf2f(hps[(size_t)r0 * 32 + j]);
            float h1 = bf2f(hps[(size_t)r1 * 32 + j]);
            float h2 = bf2f(hps[(size_t)r2 * 32 + j]);
            float h3 = bf2f(hps[(size_t)r3 * 32 + j]);
            s += h0; s += h1; s += h2; s += h3;
        }
        for (; k < m; ++k) {
            int r = __shfl(ids, k, 32);
            s += bf2f(hps[(size_t)r * 32 + j]);
        }
    }
    out[(size_t)c * 32 + j] = b2[j] - dis[c] * s;
}

extern "C" void kernel_launch(void* const* d_in, const int* in_sizes, int n_in,
                              void* d_out, int out_size, void* d_ws, size_t ws_size,
                              hipStream_t stream) {
    const float* x    = (const float*)d_in[0];
    const int*   ei   = (const int*)d_in[1];
    const int*   priv = (const int*)d_in[2];
    const float* W1   = (const float*)d_in[3];
    const float* b1   = (const float*)d_in[4];
    const float* W2   = (const float*)d_in[5];
    const float* b2   = (const float*)d_in[6];
    float* out = (float*)d_out;

    const int N = in_sizes[2];
    const int E = in_sizes[1] / 2;
    const int* row = ei;
    const int* col = ei + E;

    char* ws = (char*)d_ws;
    size_t off = 0;
    auto take = [&](size_t bytes) { char* p = ws + off; off = (off + bytes + 255) & ~(size_t)255; return p; };
    int*            hist     = (int*)           take((size_t)131072 * 4);
    int*            excl     = (int*)           take((size_t)131072 * 4);
    int*            bsum     = (int*)           take(512 * 4);
    unsigned short* W1b      = (unsigned short*)take((size_t)8192 * 2);
    unsigned short* W2b      = (unsigned short*)take((size_t)4096 * 2);
    unsigned*       cbuf     = (unsigned*)      take((size_t)E * 4);
    unsigned short* rbuf     = (unsigned short*)take((size_t)E * 2);
    float*          dis      = (float*)         take((size_t)N * 4);
    int*            cntC     = (int*)           take((size_t)N * 4);
    int*            colStart = (int*)           take((size_t)N * 4);
    unsigned short* eSrc     = (unsigned short*)take((size_t)E * 2);
    unsigned short* xt       = (unsigned short*)take((size_t)N * 64 * 2);
    unsigned short* agg1b    = (unsigned short*)take((size_t)N * 64 * 2);
    unsigned short* hps      = (unsigned short*)take((size_t)N * 32 * 2);
    (void)ws_size;

    const int chunk = (((E + 255) / 256) + 3) & ~3;   // multiple of 4 -> int4-aligned
    const int nbk = (N + 255) / 256;                  // node buckets (196 < 255)

    k_hist2   <<<256, 1024, 0, stream>>>(row, col, E, chunk, hist, W1, W2, W1b, W2b);
    k_scan_a  <<<512, 256, 0, stream>>>(hist, excl, bsum, 131072);
    k_part    <<<256, 1024, 0, stream>>>(row, col, E, chunk, excl, bsum, cbuf, rbuf);
    k_build   <<<2 * nbk, 256, 0, stream>>>(rbuf, cbuf, bsum, priv, x, N, E, nbk,
                                            dis, xt, cntC, colStart, eSrc);
    k_gather1 <<<((size_t)N * 64 + 255) / 256, 256, 0, stream>>>(xt, eSrc, colStart, cntC, dis, agg1b, N);
    k_mlp_mfma<<<(N + 63) / 64, 256, 0, stream>>>(agg1b, W1b, b1, W2b, dis, hps, N);
    k_gather2 <<<((size_t)N * 32 + 255) / 256, 256, 0, stream>>>(hps, eSrc, colStart, cntC, dis, b2, out, N);
}